// Round 8
// baseline (25.220 us; speedup 1.0000x reference)
//
#include <hip/hip_runtime.h>
#include <hip/hip_fp16.h>
#include <math.h>

#define MM 8192
#define NN 64
#define NB 25
#define MPB 8               // m's per block
#define PPT 2               // points per thread
#define KS 12               // floats per K record (10 used, 48B stride)
#define LOG2E 1.44269504088896340736f

struct Q { float w, x, y, z; };
typedef float f32x2 __attribute__((ext_vector_type(2)));

__device__ __forceinline__ Q qmul(const Q a, const Q b) {
    Q r;
    r.w = a.w*b.w - a.x*b.x - a.y*b.y - a.z*b.z;
    r.x = a.w*b.x + b.w*a.x + a.y*b.z - a.z*b.y;
    r.y = a.w*b.y + b.w*a.y + a.z*b.x - a.x*b.z;
    r.z = a.w*b.z + b.w*a.z + a.x*b.y - a.y*b.x;
    return r;
}

__device__ __forceinline__ unsigned pk_rn(float a, float b) {
    return __builtin_bit_cast(unsigned, __floats2half2_rn(a, b));
}
typedef __fp16 f16x2 __attribute__((ext_vector_type(2)));
__device__ __forceinline__ __half2 pk_rtz(float a, float b) {
    f16x2 v = __builtin_amdgcn_cvt_pkrtz(a, b);
    return __builtin_bit_cast(__half2, v);
}
__device__ __forceinline__ __half2 bc_h2(unsigned u) {
    return __builtin_bit_cast(__half2, u);
}

// ---- prep: 25 quadratic-form records (rest row 0 + log_gauss only), 1 tiny block ----
__global__ __launch_bounds__(64) void prep_kernel(
    const float* __restrict__ rest_qr, const float* __restrict__ rest_qd,
    const float* __restrict__ log_gauss, float* __restrict__ Kbuf)
{
    const int b = threadIdx.x;
    if (b >= NB) return;
    const float4 Rqv = *reinterpret_cast<const float4*>(rest_qr + b * 4);
    const float4 Rdv = *reinterpret_cast<const float4*>(rest_qd + b * 4);
    const Q Rq{Rqv.x, Rqv.y, Rqv.z, Rqv.w};
    const Q Rqc{Rq.w, -Rq.x, -Rq.y, -Rq.z};
    const Q Rdc{Rdv.x, -Rdv.y, -Rdv.z, -Rdv.w};
    const float i0 = __expf(-log_gauss[b * 3 + 0]);
    const float i1 = __expf(-log_gauss[b * 3 + 1]);
    const float i2 = __expf(-log_gauss[b * 3 + 2]);
    const Q tqb = qmul(Rdc, Rq);
    const float qw = Rqc.w, qx = Rqc.x, qy = Rqc.y, qz = Rqc.z;
    const float r00 = 1.f - 2.f*(qy*qy + qz*qz), r01 = 2.f*(qx*qy - qw*qz), r02 = 2.f*(qx*qz + qw*qy);
    const float r10 = 2.f*(qx*qy + qw*qz), r11 = 1.f - 2.f*(qx*qx + qz*qz), r12 = 2.f*(qy*qz - qw*qx);
    const float r20 = 2.f*(qx*qz - qw*qy), r21 = 2.f*(qy*qz + qw*qx), r22 = 1.f - 2.f*(qx*qx + qy*qy);
    const float g00 = r00*i0, g01 = r01*i0, g02 = r02*i0;
    const float g10 = r10*i1, g11 = r11*i1, g12 = r12*i1;
    const float g20 = r20*i2, g21 = r21*i2, g22 = r22*i2;
    const float u0 = 2.f*tqb.x*i0, u1 = 2.f*tqb.y*i1, u2 = 2.f*tqb.z*i2;
    const float c = LOG2E;
    float* kp = Kbuf + b * KS;
    *reinterpret_cast<float4*>(kp + 0) = make_float4(
        -0.5f*c*(g00*g00 + g10*g10 + g20*g20),
        -0.5f*c*(g01*g01 + g11*g11 + g21*g21),
        -0.5f*c*(g02*g02 + g12*g12 + g22*g22),
        -c*(g00*g01 + g10*g11 + g20*g21));
    *reinterpret_cast<float4*>(kp + 4) = make_float4(
        -c*(g00*g02 + g10*g12 + g20*g22),
        -c*(g01*g02 + g11*g12 + g21*g22),
        -c*(g00*u0 + g10*u1 + g20*u2),
        -c*(g01*u0 + g11*u1 + g21*u2));
    *reinterpret_cast<float4*>(kp + 8) = make_float4(
        -c*(g02*u0 + g12*u1 + g22*u2),
        -0.5f*c*(u0*u0 + u1*u1 + u2*u2), 0.f, 0.f);
}

// ---- skin: PPT=2, grid 1024, 4 waves/SIMD; kK via L1-broadcast VMEM, quats via LDS ----
__global__ __launch_bounds__(256, 4) void skin_kernel(
    const float* __restrict__ xyz,
    const float* __restrict__ t_qr,
    const float* __restrict__ t_qd,
    const float* __restrict__ rest_qr,
    const float* __restrict__ rest_qd,
    const float* __restrict__ Kb,
    float* __restrict__ out)
{
    __shared__ __align__(16) float    sref[MPB][4];       // bone-0 se_r per m
    __shared__ __align__(16) unsigned qQ[MPB][NB][4];     // packed fp16 (qr,qd) per (m,b)

    const int t  = threadIdx.x;
    const int m0 = blockIdx.x * MPB;

    // opaque zero in a VGPR: forces vector (L1-broadcast) loads for kK, vmcnt-counted
    int vz;
    asm volatile("v_mov_b32 %0, 0" : "=v"(vz));

    // -------- early xyz loads --------
    const int m_sub = t >> 5;                  // 32 threads per m
    const int pt0   = (t & 31) * PPT;
    const int pbase = ((m0 + m_sub) * NN + pt0) * 3;
    const float2 a0 = *reinterpret_cast<const float2*>(xyz + pbase);
    const float2 a1 = *reinterpret_cast<const float2*>(xyz + pbase + 2);
    const float2 a2 = *reinterpret_cast<const float2*>(xyz + pbase + 4);

    // -------- phase 1: se3 records (8 m x 25 = 200 threads) --------
    Q se_r{0,0,0,0}, se_d{0,0,0,0};
    int ms = 0, bb = 0;
    const bool act = t < MPB * NB;
    if (act) {
        ms = t / NB; bb = t - ms * NB;
        const int gbase = (m0 * NB + t) * 4;
        const float4 Tqv = *reinterpret_cast<const float4*>(t_qr + gbase);
        const float4 Tdv = *reinterpret_cast<const float4*>(t_qd + gbase);
        const float4 Rqv = *reinterpret_cast<const float4*>(rest_qr + bb * 4);
        const float4 Rdv = *reinterpret_cast<const float4*>(rest_qd + bb * 4);
        const Q Tq{Tqv.x, Tqv.y, Tqv.z, Tqv.w};
        const Q Td{Tdv.x, Tdv.y, Tdv.z, Tdv.w};
        const Q Rq{Rqv.x, Rqv.y, Rqv.z, Rqv.w};
        const Q Rqc{Rq.w, -Rq.x, -Rq.y, -Rq.z};
        const Q Rdc{Rdv.x, -Rdv.y, -Rdv.z, -Rdv.w};
        se_r = qmul(Tq, Rqc);
        const Q a1q = qmul(Tq, Rdc);
        const Q a2q = qmul(Td, Rqc);
        se_d = Q{a1q.w + a2q.w, a1q.x + a2q.x, a1q.y + a2q.y, a1q.z + a2q.z};
        if (bb == 0) *reinterpret_cast<float4*>(sref[ms]) = make_float4(se_r.w, se_r.x, se_r.y, se_r.z);
    }
    __syncthreads();
    if (act) {
        const float4 rf = *reinterpret_cast<const float4*>(sref[ms]);
        const float d0 = se_r.w*rf.x + se_r.x*rf.y + se_r.y*rf.z + se_r.z*rf.w;
        const float sg = (d0 < 0.f) ? -1.f : 1.f;
        qQ[ms][bb][0] = pk_rn(sg*se_r.w, sg*se_r.x);
        qQ[ms][bb][1] = pk_rn(sg*se_r.y, sg*se_r.z);
        qQ[ms][bb][2] = pk_rn(sg*se_d.w, sg*se_d.x);
        qQ[ms][bb][3] = pk_rn(sg*se_d.y, sg*se_d.z);
    }
    __syncthreads();

    // -------- phase 2: logits, packed fp32 over the 2 points --------
    const f32x2 pxv = {a0.x, a1.y};
    const f32x2 pyv = {a0.y, a2.x};
    const f32x2 pzv = {a1.x, a2.y};
    const f32x2 fxx = pxv*pxv, fyy = pyv*pyv, fzz = pzv*pzv;
    const f32x2 fxy = pxv*pyv, fxz = pxv*pzv, fyz = pyv*pzv;

    f32x2 lg[NB];
    f32x2 mx = {-3.4e38f, -3.4e38f};
#pragma unroll
    for (int b = 0; b < NB; ++b) {
        const float* kp = Kb + b * KS;
        const float4 kv0 = *reinterpret_cast<const float4*>(kp + vz);      // global_load_dwordx4 (L1 broadcast)
        const float4 kv1 = *reinterpret_cast<const float4*>(kp + 4 + vz);
        const float2 kv2 = *reinterpret_cast<const float2*>(kp + 8 + vz);
        const f32x2 K0 = {kv0.x, kv0.x}, K1 = {kv0.y, kv0.y}, K2 = {kv0.z, kv0.z};
        const f32x2 K3 = {kv0.w, kv0.w}, K4 = {kv1.x, kv1.x}, K5 = {kv1.y, kv1.y};
        const f32x2 K6 = {kv1.z, kv1.z}, K7 = {kv1.w, kv1.w}, K8 = {kv2.x, kv2.x};
        f32x2 s = {kv2.y, kv2.y};
        s = __builtin_elementwise_fma(K8, pzv, s);
        s = __builtin_elementwise_fma(K7, pyv, s);
        s = __builtin_elementwise_fma(K6, pxv, s);
        s = __builtin_elementwise_fma(K5, fyz, s);
        s = __builtin_elementwise_fma(K4, fxz, s);
        s = __builtin_elementwise_fma(K3, fxy, s);
        s = __builtin_elementwise_fma(K2, fzz, s);
        s = __builtin_elementwise_fma(K1, fyy, s);
        s = __builtin_elementwise_fma(K0, fxx, s);
        lg[b] = s;
        mx = __builtin_elementwise_max(mx, s);
    }

    // -------- blend (unnormalized; softmax denominator cancels) --------
    const __half2 hz = __floats2half2_rn(0.f, 0.f);
    __half2 acc[PPT][4];
#pragma unroll
    for (int p = 0; p < PPT; ++p) { acc[p][0]=hz; acc[p][1]=hz; acc[p][2]=hz; acc[p][3]=hz; }

#pragma unroll
    for (int b = 0; b < NB; ++b) {
        const uint4 qv = *reinterpret_cast<const uint4*>(&qQ[m_sub][b][0]);  // 1x ds_read_b128
        const __half2 h0 = bc_h2(qv.x), h1 = bc_h2(qv.y), h2 = bc_h2(qv.z), h3 = bc_h2(qv.w);
        const float e0 = __builtin_amdgcn_exp2f(lg[b].x - mx.x);
        const float e1 = __builtin_amdgcn_exp2f(lg[b].y - mx.y);
        const __half2 e20 = pk_rtz(e0, e0);
        const __half2 e21 = pk_rtz(e1, e1);
        acc[0][0] = __hfma2(e20, h0, acc[0][0]);
        acc[0][1] = __hfma2(e20, h1, acc[0][1]);
        acc[0][2] = __hfma2(e20, h2, acc[0][2]);
        acc[0][3] = __hfma2(e20, h3, acc[0][3]);
        acc[1][0] = __hfma2(e21, h0, acc[1][0]);
        acc[1][1] = __hfma2(e21, h1, acc[1][1]);
        acc[1][2] = __hfma2(e21, h2, acc[1][2]);
        acc[1][3] = __hfma2(e21, h3, acc[1][3]);
    }

    // -------- epilogue --------
    float px[PPT] = {pxv.x, pxv.y};
    float py[PPT] = {pyv.x, pyv.y};
    float pz[PPT] = {pzv.x, pzv.y};
    float o[PPT*3];
#pragma unroll
    for (int p = 0; p < PPT; ++p) {
        const float aw = __low2float(acc[p][0]), ax = __high2float(acc[p][0]);
        const float ay = __low2float(acc[p][1]), az = __high2float(acc[p][1]);
        const float bw = __low2float(acc[p][2]), bx = __high2float(acc[p][2]);
        const float by = __low2float(acc[p][3]), bz = __high2float(acc[p][3]);

        const float inv = rsqrtf(aw*aw + ax*ax + ay*ay + az*az);
        const Q qr{aw*inv, ax*inv, ay*inv, az*inv};
        const Q qd{bw*inv, bx*inv, by*inv, bz*inv};
        const Q qrc{qr.w, -qr.x, -qr.y, -qr.z};
        const Q tq = qmul(qd, qrc);

        const float uvx = qr.y*pz[p] - qr.z*py[p];
        const float uvy = qr.z*px[p] - qr.x*pz[p];
        const float uvz = qr.x*py[p] - qr.y*px[p];
        const float cx = qr.y*uvz - qr.z*uvy;
        const float cy = qr.z*uvx - qr.x*uvz;
        const float cz = qr.x*uvy - qr.y*uvx;

        o[p*3+0] = px[p] + 2.f*(qr.w*uvx + cx) + 2.f*tq.x;
        o[p*3+1] = py[p] + 2.f*(qr.w*uvy + cy) + 2.f*tq.y;
        o[p*3+2] = pz[p] + 2.f*(qr.w*uvz + cz) + 2.f*tq.z;
    }

    *reinterpret_cast<float2*>(out + pbase)     = make_float2(o[0], o[1]);
    *reinterpret_cast<float2*>(out + pbase + 2) = make_float2(o[2], o[3]);
    *reinterpret_cast<float2*>(out + pbase + 4) = make_float2(o[4], o[5]);
}

extern "C" void kernel_launch(void* const* d_in, const int* in_sizes, int n_in,
                              void* d_out, int out_size, void* d_ws, size_t ws_size,
                              hipStream_t stream) {
    const float* xyz       = (const float*)d_in[0];
    const float* t_qr      = (const float*)d_in[1];
    const float* t_qd      = (const float*)d_in[2];
    const float* rest_qr   = (const float*)d_in[3];
    const float* rest_qd   = (const float*)d_in[4];
    const float* log_gauss = (const float*)d_in[5];
    float* out  = (float*)d_out;
    float* Kbuf = (float*)d_ws;    // 25*12*4 = 1200 B

    hipLaunchKernelGGL(prep_kernel, dim3(1), dim3(64), 0, stream,
                       rest_qr, rest_qd, log_gauss, Kbuf);
    hipLaunchKernelGGL(skin_kernel, dim3(MM / MPB), dim3(256), 0, stream,
                       xyz, t_qr, t_qd, rest_qr, rest_qd, Kbuf, out);
}

// Round 9
// 19.080 us; speedup vs baseline: 1.3218x; 1.3218x over previous
//
#include <hip/hip_runtime.h>
#include <hip/hip_fp16.h>
#include <math.h>

#define MM 8192
#define NN 64
#define NB 25
#define MPB 16              // m's per block
#define PPT 4               // points per thread
#define LOG2E 1.44269504088896340736f

struct Q { float w, x, y, z; };

__device__ __forceinline__ Q qmul(const Q a, const Q b) {
    Q r;
    r.w = a.w*b.w - a.x*b.x - a.y*b.y - a.z*b.z;
    r.x = a.w*b.x + b.w*a.x + a.y*b.z - a.z*b.y;
    r.y = a.w*b.y + b.w*a.y + a.z*b.x - a.x*b.z;
    r.z = a.w*b.z + b.w*a.z + a.x*b.y - a.y*b.x;
    return r;
}

__device__ __forceinline__ unsigned pk_rn(float a, float b) {
    return __builtin_bit_cast(unsigned, __floats2half2_rn(a, b));
}

typedef __fp16 f16x2 __attribute__((ext_vector_type(2)));
__device__ __forceinline__ __half2 pk_rtz(float a, float b) {
    f16x2 v = __builtin_amdgcn_cvt_pkrtz(a, b);
    return __builtin_bit_cast(__half2, v);
}
__device__ __forceinline__ __half2 bc_h2(unsigned u) {
    return __builtin_bit_cast(__half2, u);
}

__global__ __launch_bounds__(256, 2) void skin_kernel(
    const float* __restrict__ xyz,
    const float* __restrict__ t_qr,
    const float* __restrict__ t_qd,
    const float* __restrict__ rest_qr,
    const float* __restrict__ rest_qd,
    const float* __restrict__ log_gauss,
    float* __restrict__ out)
{
    __shared__ __align__(16) float   kK[NB][12];          // fp32 quadratic-form coeffs
    __shared__ __align__(16) float   sref[MPB][4];        // bone-0 se_r per m (hemisphere ref)
    __shared__ __align__(16) unsigned qQ[MPB][NB][4];     // packed fp16 (qr,qd) per (m,b)

    const int t  = threadIdx.x;
    const int m0 = blockIdx.x * MPB;

    // ---------- phase 0: K table (rest row 0 + log_gauss only) ----------
    if (t < NB) {
        const int b = t;
        const float4 Rqv = *reinterpret_cast<const float4*>(rest_qr + b * 4);
        const float4 Rdv = *reinterpret_cast<const float4*>(rest_qd + b * 4);
        const Q Rq{Rqv.x, Rqv.y, Rqv.z, Rqv.w};
        const Q Rqc{Rq.w, -Rq.x, -Rq.y, -Rq.z};
        const Q Rdc{Rdv.x, -Rdv.y, -Rdv.z, -Rdv.w};
        const float i0 = __expf(-log_gauss[b * 3 + 0]);
        const float i1 = __expf(-log_gauss[b * 3 + 1]);
        const float i2 = __expf(-log_gauss[b * 3 + 2]);
        const Q tqb = qmul(Rdc, Rq);
        const float qw = Rqc.w, qx = Rqc.x, qy = Rqc.y, qz = Rqc.z;
        const float r00 = 1.f - 2.f*(qy*qy + qz*qz), r01 = 2.f*(qx*qy - qw*qz), r02 = 2.f*(qx*qz + qw*qy);
        const float r10 = 2.f*(qx*qy + qw*qz), r11 = 1.f - 2.f*(qx*qx + qz*qz), r12 = 2.f*(qy*qz - qw*qx);
        const float r20 = 2.f*(qx*qz - qw*qy), r21 = 2.f*(qy*qz + qw*qx), r22 = 1.f - 2.f*(qx*qx + qy*qy);
        const float g00 = r00*i0, g01 = r01*i0, g02 = r02*i0;
        const float g10 = r10*i1, g11 = r11*i1, g12 = r12*i1;
        const float g20 = r20*i2, g21 = r21*i2, g22 = r22*i2;
        const float u0 = 2.f*tqb.x*i0, u1 = 2.f*tqb.y*i1, u2 = 2.f*tqb.z*i2;
        const float c = LOG2E;
        kK[b][0] = -0.5f*c*(g00*g00 + g10*g10 + g20*g20);
        kK[b][1] = -0.5f*c*(g01*g01 + g11*g11 + g21*g21);
        kK[b][2] = -0.5f*c*(g02*g02 + g12*g12 + g22*g22);
        kK[b][3] = -c*(g00*g01 + g10*g11 + g20*g21);
        kK[b][4] = -c*(g00*g02 + g10*g12 + g20*g22);
        kK[b][5] = -c*(g01*g02 + g11*g12 + g21*g22);
        kK[b][6] = -c*(g00*u0 + g10*u1 + g20*u2);
        kK[b][7] = -c*(g01*u0 + g11*u1 + g21*u2);
        kK[b][8] = -c*(g02*u0 + g12*u1 + g22*u2);
        kK[b][9] = -0.5f*c*(u0*u0 + u1*u1 + u2*u2);
    }

    // ---------- phase 1: se3 records (16 m x 25 = 400; threads do 1-2 each) ----------
    Q se_r1{0,0,0,0}, se_d1{0,0,0,0}, se_r2{0,0,0,0}, se_d2{0,0,0,0};
    int ms1 = 0, b1 = 0, ms2 = 0, b2 = 0;
    {
        const int r = t;
        ms1 = r / NB; b1 = r - ms1 * NB;
        const int gbase = (m0 * NB + r) * 4;
        const float4 Tqv = *reinterpret_cast<const float4*>(t_qr + gbase);
        const float4 Tdv = *reinterpret_cast<const float4*>(t_qd + gbase);
        const float4 Rqv = *reinterpret_cast<const float4*>(rest_qr + b1 * 4);
        const float4 Rdv = *reinterpret_cast<const float4*>(rest_qd + b1 * 4);
        const Q Tq{Tqv.x, Tqv.y, Tqv.z, Tqv.w};
        const Q Td{Tdv.x, Tdv.y, Tdv.z, Tdv.w};
        const Q Rq{Rqv.x, Rqv.y, Rqv.z, Rqv.w};
        const Q Rqc{Rq.w, -Rq.x, -Rq.y, -Rq.z};
        const Q Rdc{Rdv.x, -Rdv.y, -Rdv.z, -Rdv.w};
        se_r1 = qmul(Tq, Rqc);
        const Q a1 = qmul(Tq, Rdc);
        const Q a2 = qmul(Td, Rqc);
        se_d1 = Q{a1.w + a2.w, a1.x + a2.x, a1.y + a2.y, a1.z + a2.z};
        if (b1 == 0) *reinterpret_cast<float4*>(sref[ms1]) = make_float4(se_r1.w, se_r1.x, se_r1.y, se_r1.z);
    }
    const bool has2 = (t + 256) < (MPB * NB);
    if (has2) {
        const int r = t + 256;
        ms2 = r / NB; b2 = r - ms2 * NB;
        const int gbase = (m0 * NB + r) * 4;
        const float4 Tqv = *reinterpret_cast<const float4*>(t_qr + gbase);
        const float4 Tdv = *reinterpret_cast<const float4*>(t_qd + gbase);
        const float4 Rqv = *reinterpret_cast<const float4*>(rest_qr + b2 * 4);
        const float4 Rdv = *reinterpret_cast<const float4*>(rest_qd + b2 * 4);
        const Q Tq{Tqv.x, Tqv.y, Tqv.z, Tqv.w};
        const Q Td{Tdv.x, Tdv.y, Tdv.z, Tdv.w};
        const Q Rq{Rqv.x, Rqv.y, Rqv.z, Rqv.w};
        const Q Rqc{Rq.w, -Rq.x, -Rq.y, -Rq.z};
        const Q Rdc{Rdv.x, -Rdv.y, -Rdv.z, -Rdv.w};
        se_r2 = qmul(Tq, Rqc);
        const Q a1 = qmul(Tq, Rdc);
        const Q a2 = qmul(Td, Rqc);
        se_d2 = Q{a1.w + a2.w, a1.x + a2.x, a1.y + a2.y, a1.z + a2.z};
        if (b2 == 0) *reinterpret_cast<float4*>(sref[ms2]) = make_float4(se_r2.w, se_r2.x, se_r2.y, se_r2.z);
    }
    __syncthreads();

    {   // sign-fix + pack to fp16
        const float4 rf = *reinterpret_cast<const float4*>(sref[ms1]);
        const float d0 = se_r1.w*rf.x + se_r1.x*rf.y + se_r1.y*rf.z + se_r1.z*rf.w;
        const float sg = (d0 < 0.f) ? -1.f : 1.f;
        qQ[ms1][b1][0] = pk_rn(sg*se_r1.w, sg*se_r1.x);
        qQ[ms1][b1][1] = pk_rn(sg*se_r1.y, sg*se_r1.z);
        qQ[ms1][b1][2] = pk_rn(sg*se_d1.w, sg*se_d1.x);
        qQ[ms1][b1][3] = pk_rn(sg*se_d1.y, sg*se_d1.z);
    }
    if (has2) {
        const float4 rf = *reinterpret_cast<const float4*>(sref[ms2]);
        const float d0 = se_r2.w*rf.x + se_r2.x*rf.y + se_r2.y*rf.z + se_r2.z*rf.w;
        const float sg = (d0 < 0.f) ? -1.f : 1.f;
        qQ[ms2][b2][0] = pk_rn(sg*se_r2.w, sg*se_r2.x);
        qQ[ms2][b2][1] = pk_rn(sg*se_r2.y, sg*se_r2.z);
        qQ[ms2][b2][2] = pk_rn(sg*se_d2.w, sg*se_d2.x);
        qQ[ms2][b2][3] = pk_rn(sg*se_d2.y, sg*se_d2.z);
    }
    __syncthreads();

    // ---------- phase 2: FUSED online-softmax main loop ----------
    const int m_sub = t >> 4;                 // 16 threads per m
    const int pt0   = (t & 15) * PPT;
    const int pbase = ((m0 + m_sub) * NN + pt0) * 3;

    const float4 v0 = *reinterpret_cast<const float4*>(xyz + pbase);
    const float4 v1 = *reinterpret_cast<const float4*>(xyz + pbase + 4);
    const float4 v2 = *reinterpret_cast<const float4*>(xyz + pbase + 8);
    float px[PPT], py[PPT], pz[PPT];
    px[0]=v0.x; py[0]=v0.y; pz[0]=v0.z;
    px[1]=v0.w; py[1]=v1.x; pz[1]=v1.y;
    px[2]=v1.z; py[2]=v1.w; pz[2]=v2.x;
    px[3]=v2.y; py[3]=v2.z; pz[3]=v2.w;

    float fxx[PPT], fyy[PPT], fzz[PPT], fxy[PPT], fxz[PPT], fyz[PPT];
#pragma unroll
    for (int p = 0; p < PPT; ++p) {
        fxx[p]=px[p]*px[p]; fyy[p]=py[p]*py[p]; fzz[p]=pz[p]*pz[p];
        fxy[p]=px[p]*py[p]; fxz[p]=px[p]*pz[p]; fyz[p]=py[p]*pz[p];
    }

    // running max M[p], fp16 accumulators; any common scale cancels at normalization
    float M[PPT];
    __half2 acc[PPT][4];

    {   // bone 0 peel: e = 1 -> acc = quat
        const uint4 qv = *reinterpret_cast<const uint4*>(&qQ[m_sub][0][0]);
        const float k0=kK[0][0], k1=kK[0][1], k2=kK[0][2], k3=kK[0][3], k4=kK[0][4];
        const float k5=kK[0][5], k6=kK[0][6], k7=kK[0][7], k8=kK[0][8], k9=kK[0][9];
#pragma unroll
        for (int p = 0; p < PPT; ++p) {
            float s = fmaf(k8, pz[p], k9);
            s = fmaf(k7, py[p], s);
            s = fmaf(k6, px[p], s);
            s = fmaf(k5, fyz[p], s);
            s = fmaf(k4, fxz[p], s);
            s = fmaf(k3, fxy[p], s);
            s = fmaf(k2, fzz[p], s);
            s = fmaf(k1, fyy[p], s);
            s = fmaf(k0, fxx[p], s);
            M[p] = s;
            acc[p][0] = bc_h2(qv.x);
            acc[p][1] = bc_h2(qv.y);
            acc[p][2] = bc_h2(qv.z);
            acc[p][3] = bc_h2(qv.w);
        }
    }

#pragma unroll
    for (int b = 1; b < NB; ++b) {
        const uint4 qv = *reinterpret_cast<const uint4*>(&qQ[m_sub][b][0]);  // 1x ds_read_b128
        const __half2 h0 = bc_h2(qv.x), h1 = bc_h2(qv.y), h2 = bc_h2(qv.z), h3 = bc_h2(qv.w);
        const float k0=kK[b][0], k1=kK[b][1], k2=kK[b][2], k3=kK[b][3], k4=kK[b][4];
        const float k5=kK[b][5], k6=kK[b][6], k7=kK[b][7], k8=kK[b][8], k9=kK[b][9];
#pragma unroll
        for (int p = 0; p < PPT; ++p) {
            float s = fmaf(k8, pz[p], k9);
            s = fmaf(k7, py[p], s);
            s = fmaf(k6, px[p], s);
            s = fmaf(k5, fyz[p], s);
            s = fmaf(k4, fxz[p], s);
            s = fmaf(k3, fxy[p], s);
            s = fmaf(k2, fzz[p], s);
            s = fmaf(k1, fyy[p], s);
            s = fmaf(k0, fxx[p], s);
            // branchless online rescale: common factors cancel at normalization
            const float d  = s - M[p];
            const float dp = fmaxf(d, 0.f);           // rescale amount
            M[p] += dp;                                // = max(M, s)
            const float e  = __builtin_amdgcn_exp2f(d - dp);   // <= 1
            const float sc = __builtin_amdgcn_exp2f(-dp);      // 1 when no rescale
            const __half2 e2 = pk_rtz(e, e);
            const __half2 s2 = pk_rtz(sc, sc);
            acc[p][0] = __hfma2(acc[p][0], s2, __hmul2(e2, h0));
            acc[p][1] = __hfma2(acc[p][1], s2, __hmul2(e2, h1));
            acc[p][2] = __hfma2(acc[p][2], s2, __hmul2(e2, h2));
            acc[p][3] = __hfma2(acc[p][3], s2, __hmul2(e2, h3));
        }
    }

    // ---------- epilogue ----------
    float o[12];
#pragma unroll
    for (int p = 0; p < PPT; ++p) {
        const float aw = __low2float(acc[p][0]), ax = __high2float(acc[p][0]);
        const float ay = __low2float(acc[p][1]), az = __high2float(acc[p][1]);
        const float bw = __low2float(acc[p][2]), bx = __high2float(acc[p][2]);
        const float by = __low2float(acc[p][3]), bz = __high2float(acc[p][3]);

        const float inv = rsqrtf(aw*aw + ax*ax + ay*ay + az*az);
        const Q qr{aw*inv, ax*inv, ay*inv, az*inv};
        const Q qd{bw*inv, bx*inv, by*inv, bz*inv};
        const Q qrc{qr.w, -qr.x, -qr.y, -qr.z};
        const Q tq = qmul(qd, qrc);

        const float uvx = qr.y*pz[p] - qr.z*py[p];
        const float uvy = qr.z*px[p] - qr.x*pz[p];
        const float uvz = qr.x*py[p] - qr.y*px[p];
        const float cx = qr.y*uvz - qr.z*uvy;
        const float cy = qr.z*uvx - qr.x*uvz;
        const float cz = qr.x*uvy - qr.y*uvx;

        o[p*3+0] = px[p] + 2.f*(qr.w*uvx + cx) + 2.f*tq.x;
        o[p*3+1] = py[p] + 2.f*(qr.w*uvy + cy) + 2.f*tq.y;
        o[p*3+2] = pz[p] + 2.f*(qr.w*uvz + cz) + 2.f*tq.z;
    }

    *reinterpret_cast<float4*>(out + pbase)     = make_float4(o[0], o[1], o[2],  o[3]);
    *reinterpret_cast<float4*>(out + pbase + 4) = make_float4(o[4], o[5], o[6],  o[7]);
    *reinterpret_cast<float4*>(out + pbase + 8) = make_float4(o[8], o[9], o[10], o[11]);
}

extern "C" void kernel_launch(void* const* d_in, const int* in_sizes, int n_in,
                              void* d_out, int out_size, void* d_ws, size_t ws_size,
                              hipStream_t stream) {
    const float* xyz       = (const float*)d_in[0];
    const float* t_qr      = (const float*)d_in[1];
    const float* t_qd      = (const float*)d_in[2];
    const float* rest_qr   = (const float*)d_in[3];
    const float* rest_qd   = (const float*)d_in[4];
    const float* log_gauss = (const float*)d_in[5];
    float* out = (float*)d_out;

    hipLaunchKernelGGL(skin_kernel, dim3(MM / MPB), dim3(256), 0, stream,
                       xyz, t_qr, t_qd, rest_qr, rest_qd, log_gauss, out);
}